// Round 11
// baseline (195.549 us; speedup 1.0000x reference)
//
#include <hip/hip_runtime.h>
#include <hip/hip_bf16.h>

#define NFFT 8192
#define NH   4096
#define D    1024
#define NSEQ 4096
#define NDP  512
#define BATCH 4
#define NT   512
#define TSLOT 4097
#define PI_D 3.14159265358979323846

// 16-pt DFT internal constants
#define C1 0.92387953251128675613f
#define S1 0.38268343236508977173f
#define RT 0.70710678118654752440f

__device__ __forceinline__ int SWZ(int i) { return i ^ ((i >> 4) & 15) ^ ((i >> 8) & 15); }

__device__ __forceinline__ float2 cadd(float2 a, float2 b){ return make_float2(a.x+b.x, a.y+b.y); }
__device__ __forceinline__ float2 csub(float2 a, float2 b){ return make_float2(a.x-b.x, a.y-b.y); }
__device__ __forceinline__ float2 cmul(float2 a, float2 w){ return make_float2(a.x*w.x - a.y*w.y, a.x*w.y + a.y*w.x); }
__device__ __forceinline__ float2 cmulc(float2 a, float2 w){ return make_float2(a.x*w.x + a.y*w.y, a.y*w.x - a.x*w.y); }

// digit-reversal for radices [2,16,16,16] DIF (radix-2 first, stride 4096)
__device__ __forceinline__ int drev16(int k) {
    return ((k & 1) << 12) | (((k >> 1) & 15) << 8) | (((k >> 5) & 15) << 4) | ((k >> 9) & 15);
}
// bank-aware bijection tid(9b) x it(3b) -> k in [0,4096)
__device__ __forceinline__ int kmap16(int tid, int it) {
    return ((tid >> 7) & 3) | (it << 2) | ((tid & 15) << 5) | (((tid >> 4) & 7) << 9);
}

__global__ __launch_bounds__(256) void wtab_init(float2* __restrict__ wtab) {
    int m = blockIdx.x * 256 + threadIdx.x;   // grid 16 -> 4096 entries
    double a = -2.0 * PI_D * (double)m / (double)NFFT;
    wtab[m] = make_float2((float)cos(a), (float)sin(a));
}

// One radix-16 pass over LDS. Thread owns 16 points at stride H within its group.
template<int H, bool TW, bool INV>
__device__ __forceinline__ void pass16(float2* zs, const float2* __restrict__ wt, int t) {
    int blk = t >> 8;
    int i0, tw1i;
    if (H == 256)      { int j = t & 255;                      i0 = blk*4096 + j;           tw1i = 2*j;  }
    else if (H == 16)  { int g = (t>>4) & 15; int j = t & 15;  i0 = blk*4096 + g*256 + j;   tw1i = 32*j; }
    else               { int g = t & 255;                      i0 = blk*4096 + g*16;        tw1i = 0;    }

    float2 w1, w2, w3, w4, w8, w12;
    if (TW) {
        w1 = wt[tw1i];
        w2 = cmul(w1, w1);  w3 = cmul(w2, w1);
        w4 = cmul(w2, w2);  w8 = cmul(w4, w4);  w12 = cmul(w8, w4);
    }

    float2 v[16];
    #pragma unroll
    for (int q = 0; q < 16; ++q) v[q] = zs[SWZ(i0 + H*q)];

    if (INV && TW) {
        v[1]=cmulc(v[1],w1);  v[2]=cmulc(v[2],w2);  v[3]=cmulc(v[3],w3);
        v[4]=cmulc(v[4],w4);  v[5]=cmulc(v[5],cmul(w4,w1));  v[6]=cmulc(v[6],cmul(w4,w2));  v[7]=cmulc(v[7],cmul(w4,w3));
        v[8]=cmulc(v[8],w8);  v[9]=cmulc(v[9],cmul(w8,w1));  v[10]=cmulc(v[10],cmul(w8,w2)); v[11]=cmulc(v[11],cmul(w8,w3));
        v[12]=cmulc(v[12],w12); v[13]=cmulc(v[13],cmul(w12,w1)); v[14]=cmulc(v[14],cmul(w12,w2)); v[15]=cmulc(v[15],cmul(w12,w3));
    }

    // layer 1
    float2 s[4][4];
    #pragma unroll
    for (int i = 0; i < 4; ++i) {
        float2 z0=v[i], z1=v[i+4], z2=v[i+8], z3=v[i+12];
        float2 A=cadd(z0,z2), Cc=csub(z0,z2), B=cadd(z1,z3), Dd=csub(z1,z3);
        s[i][0] = cadd(A,B);
        s[i][2] = csub(A,B);
        if (!INV) { s[i][1] = make_float2(Cc.x+Dd.y, Cc.y-Dd.x);
                    s[i][3] = make_float2(Cc.x-Dd.y, Cc.y+Dd.x); }
        else      { s[i][1] = make_float2(Cc.x-Dd.y, Cc.y+Dd.x);
                    s[i][3] = make_float2(Cc.x+Dd.y, Cc.y-Dd.x); }
    }
    // internal twiddles W16^{i*o} (conj for INV)
    if (!INV) {
        s[1][1]=cmul(s[1][1],make_float2(C1,-S1)); s[1][2]=cmul(s[1][2],make_float2(RT,-RT)); s[1][3]=cmul(s[1][3],make_float2(S1,-C1));
        s[2][1]=cmul(s[2][1],make_float2(RT,-RT)); s[2][2]=make_float2(s[2][2].y,-s[2][2].x); s[2][3]=cmul(s[2][3],make_float2(-RT,-RT));
        s[3][1]=cmul(s[3][1],make_float2(S1,-C1)); s[3][2]=cmul(s[3][2],make_float2(-RT,-RT)); s[3][3]=cmul(s[3][3],make_float2(-C1,S1));
    } else {
        s[1][1]=cmul(s[1][1],make_float2(C1,S1));  s[1][2]=cmul(s[1][2],make_float2(RT,RT));  s[1][3]=cmul(s[1][3],make_float2(S1,C1));
        s[2][1]=cmul(s[2][1],make_float2(RT,RT));  s[2][2]=make_float2(-s[2][2].y,s[2][2].x); s[2][3]=cmul(s[2][3],make_float2(-RT,RT));
        s[3][1]=cmul(s[3][1],make_float2(S1,C1));  s[3][2]=cmul(s[3][2],make_float2(-RT,RT)); s[3][3]=cmul(s[3][3],make_float2(-C1,-S1));
    }
    // layer 2
    float2 y[16];
    #pragma unroll
    for (int o = 0; o < 4; ++o) {
        float2 z0=s[0][o], z1=s[1][o], z2=s[2][o], z3=s[3][o];
        float2 A=cadd(z0,z2), Cc=csub(z0,z2), B=cadd(z1,z3), Dd=csub(z1,z3);
        y[o]    = cadd(A,B);
        y[o+8]  = csub(A,B);
        if (!INV) { y[o+4]  = make_float2(Cc.x+Dd.y, Cc.y-Dd.x);
                    y[o+12] = make_float2(Cc.x-Dd.y, Cc.y+Dd.x); }
        else      { y[o+4]  = make_float2(Cc.x-Dd.y, Cc.y+Dd.x);
                    y[o+12] = make_float2(Cc.x+Dd.y, Cc.y-Dd.x); }
    }

    if (!INV && TW) {
        y[1]=cmul(y[1],w1);  y[2]=cmul(y[2],w2);  y[3]=cmul(y[3],w3);
        y[4]=cmul(y[4],w4);  y[5]=cmul(y[5],cmul(w4,w1));  y[6]=cmul(y[6],cmul(w4,w2));  y[7]=cmul(y[7],cmul(w4,w3));
        y[8]=cmul(y[8],w8);  y[9]=cmul(y[9],cmul(w8,w1));  y[10]=cmul(y[10],cmul(w8,w2)); y[11]=cmul(y[11],cmul(w8,w3));
        y[12]=cmul(y[12],w12); y[13]=cmul(y[13],cmul(w12,w1)); y[14]=cmul(y[14],cmul(w12,w2)); y[15]=cmul(y[15],cmul(w12,w3));
    }
    #pragma unroll
    for (int r = 0; r < 16; ++r) zs[SWZ(i0 + H*r)] = y[r];
}

// ---------- tspec: strided t read (XCD swizzle), fwd FFT, untangle -> slot-ordered T ----------
__global__ __launch_bounds__(NT, 2) void tspec_kernel(const float* __restrict__ tg,
                                                      const float2* __restrict__ wt,
                                                      float4* __restrict__ tspecU) {
    __shared__ float2 zs[NFFT];
    int wg = blockIdx.x;
    int dp = ((wg & 7) << 6) | (wg >> 3);   // bijective [0,512): 8 line-sharing blocks per XCD
    int t  = threadIdx.x;

    const float* tb = tg + 2 * dp;
    #pragma unroll
    for (int it = 0; it < 8; ++it) {
        int idx = t + it * NT;
        float2 v0 = *(const float2*)(tb + (size_t)idx * D);
        float2 v1 = *(const float2*)(tb + (size_t)(idx + NH) * D);
        zs[SWZ(idx)]      = cadd(v0, v1);
        zs[SWZ(idx + NH)] = cmul(csub(v0, v1), wt[idx]);
    }
    __syncthreads();
    pass16<256, true,  false>(zs, wt, t); __syncthreads();
    pass16<16,  true,  false>(zs, wt, t); __syncthreads();
    pass16<1,   false, false>(zs, wt, t); __syncthreads();

    float4* o = tspecU + (size_t)dp * TSLOT;
    #pragma unroll
    for (int it = 0; it < 8; ++it) {
        int k  = kmap16(t, it);
        int p1 = drev16(k);
        int p2 = drev16((NFFT - k) & (NFFT - 1));
        float2 z1 = zs[SWZ(p1)], z2 = zs[SWZ(p2)];
        o[it * NT + t] = make_float4(0.5f*(z1.x + z2.x), 0.5f*(z1.y - z2.y),
                                     0.5f*(z1.y + z2.y), 0.5f*(z2.x - z1.x));
    }
    if (t == 0) {   // Nyquist bin k=4096 at position drev16(4096)=8
        float2 zn = zs[SWZ(8)];
        o[4096] = make_float4(zn.x, 0.f, zn.y, 0.f);
    }
}

// ---------- conv (packed): grid (NDP, BATCH); T prefetched to regs before fwd FFT ----------
__global__ __launch_bounds__(NT, 2) void conv_kernel_p(float2* __restrict__ xP,
                                                       const float2* __restrict__ wt,
                                                       const float4* __restrict__ tspecU) {
    __shared__ float2 zs[NFFT];
    int t  = threadIdx.x;
    int dp = blockIdx.x;
    int b  = blockIdx.y;

    // T-prefetch: issue all 8 coalesced dwordx4 loads first; used only at untangle
    // (~3 FFT passes later) -> latency fully hidden. +32 VGPR (84 -> ~116 < 128 cap).
    const float4* ts4 = tspecU + (size_t)dp * TSLOT;
    float4 Tp[8];
    #pragma unroll
    for (int it = 0; it < 8; ++it) Tp[it] = ts4[it * NT + t];

    float2* slab = xP + ((size_t)dp * BATCH + b) * NSEQ;
    #pragma unroll
    for (int it = 0; it < 8; ++it) {
        int idx = t + it * NT;
        float2 v = slab[idx];
        zs[SWZ(idx)]      = v;                     // x + 0
        zs[SWZ(idx + NH)] = cmul(v, wt[idx]);      // (x - 0)*W^idx
    }
    __syncthreads();
    pass16<256, true,  false>(zs, wt, t); __syncthreads();
    pass16<16,  true,  false>(zs, wt, t); __syncthreads();
    pass16<1,   false, false>(zs, wt, t); __syncthreads();

    // untangle * multiply * repack (T already in registers)
    #pragma unroll
    for (int it = 0; it < 8; ++it) {
        int k  = kmap16(t, it);
        int p1 = drev16(k);
        int p2 = drev16((NFFT - k) & (NFFT - 1));
        float2 z1 = zs[SWZ(p1)], z2 = zs[SWZ(p2)];
        float4 T  = Tp[it];
        float x0r = 0.5f*(z1.x + z2.x), x0i = 0.5f*(z1.y - z2.y);
        float x1r = 0.5f*(z1.y + z2.y), x1i = 0.5f*(z2.x - z1.x);
        float y0r = x0r*T.x - x0i*T.y, y0i = x0r*T.y + x0i*T.x;
        float y1r = x1r*T.z - x1i*T.w, y1i = x1r*T.w + x1i*T.z;
        zs[SWZ(p1)] = make_float2(y0r - y1i, y0i + y1r);
        zs[SWZ(p2)] = make_float2(y0r + y1i, y1r - y0i);
    }
    if (t == 0) {
        float4 T = ts4[4096];
        float2 zn = zs[SWZ(8)];
        zs[SWZ(8)] = make_float2(zn.x * T.x, zn.y * T.z);
    }
    __syncthreads();

    pass16<1,   false, true>(zs, wt, t); __syncthreads();
    pass16<16,  true,  true>(zs, wt, t); __syncthreads();
    pass16<256, true,  true>(zs, wt, t); __syncthreads();

    // final radix-2 (only n < 4096) fused with packed store
    const float sc = 1.0f / (float)NFFT;
    #pragma unroll
    for (int it = 0; it < 8; ++it) {
        int n = t + it * NT;
        float2 a  = zs[SWZ(n)];
        float2 bb = zs[SWZ(n + NH)];
        float2 r  = cadd(a, cmulc(bb, wt[n]));
        slab[n] = make_float2(r.x * sc, r.y * sc);
    }
}

// ---------- conv (strided fallback, round-10 proven) ----------
__global__ __launch_bounds__(NT, 2) void conv_kernel_s(const float* __restrict__ xg,
                                                       float* __restrict__ outg,
                                                       const float2* __restrict__ wt,
                                                       const float4* __restrict__ tspecU) {
    __shared__ float2 zs[NFFT];
    int wg = blockIdx.x;
    int xcd = wg & 7, ix = wg >> 3;
    int b  = ix >> 6;
    int dp = (xcd << 6) | (ix & 63);
    int t  = threadIdx.x;

    const float4* ts4 = tspecU + (size_t)dp * TSLOT;
    float4 Tp[8];
    #pragma unroll
    for (int it = 0; it < 8; ++it) Tp[it] = ts4[it * NT + t];

    const float* xb = xg + (size_t)b * NSEQ * D + 2 * dp;
    #pragma unroll
    for (int it = 0; it < 8; ++it) {
        int idx = t + it * NT;
        float2 v = *(const float2*)(xb + (size_t)idx * D);
        zs[SWZ(idx)]      = v;
        zs[SWZ(idx + NH)] = cmul(v, wt[idx]);
    }
    __syncthreads();
    pass16<256, true,  false>(zs, wt, t); __syncthreads();
    pass16<16,  true,  false>(zs, wt, t); __syncthreads();
    pass16<1,   false, false>(zs, wt, t); __syncthreads();

    #pragma unroll
    for (int it = 0; it < 8; ++it) {
        int k  = kmap16(t, it);
        int p1 = drev16(k);
        int p2 = drev16((NFFT - k) & (NFFT - 1));
        float2 z1 = zs[SWZ(p1)], z2 = zs[SWZ(p2)];
        float4 T  = Tp[it];
        float x0r = 0.5f*(z1.x + z2.x), x0i = 0.5f*(z1.y - z2.y);
        float x1r = 0.5f*(z1.y + z2.y), x1i = 0.5f*(z2.x - z1.x);
        float y0r = x0r*T.x - x0i*T.y, y0i = x0r*T.y + x0i*T.x;
        float y1r = x1r*T.z - x1i*T.w, y1i = x1r*T.w + x1i*T.z;
        zs[SWZ(p1)] = make_float2(y0r - y1i, y0i + y1r);
        zs[SWZ(p2)] = make_float2(y0r + y1i, y1r - y0i);
    }
    if (t == 0) {
        float4 T = ts4[4096];
        float2 zn = zs[SWZ(8)];
        zs[SWZ(8)] = make_float2(zn.x * T.x, zn.y * T.z);
    }
    __syncthreads();

    pass16<1,   false, true>(zs, wt, t); __syncthreads();
    pass16<16,  true,  true>(zs, wt, t); __syncthreads();
    pass16<256, true,  true>(zs, wt, t); __syncthreads();

    const float sc = 1.0f / (float)NFFT;
    float* ob = outg + (size_t)b * NSEQ * D + 2 * dp;
    #pragma unroll
    for (int it = 0; it < 8; ++it) {
        int n = t + it * NT;
        float2 a  = zs[SWZ(n)];
        float2 bb = zs[SWZ(n + NH)];
        float2 r  = cadd(a, cmulc(bb, wt[n]));
        *(float2*)(ob + (size_t)n * D) = make_float2(r.x * sc, r.y * sc);
    }
}

// ---------- transpose/pack: (b,n,d) f32 -> (dp, b, n) float2 ----------
__global__ __launch_bounds__(256) void pack_kernel(const float* __restrict__ in,
                                                   float2* __restrict__ outp,
                                                   int Nrows, int Bsz) {
    __shared__ float tile[64][65];
    int tid = threadIdx.x;
    int n0 = blockIdx.x * 64;
    int d0 = blockIdx.y * 64;
    int b  = blockIdx.z;
    const float* ib = in + (size_t)b * Nrows * D;
    #pragma unroll
    for (int it = 0; it < 16; ++it) {
        int n_l = it * 4 + (tid >> 6);
        int d_l = tid & 63;
        tile[n_l][d_l] = ib[(size_t)(n0 + n_l) * D + d0 + d_l];
    }
    __syncthreads();
    #pragma unroll
    for (int it = 0; it < 8; ++it) {
        int flat = it * 256 + tid;
        int dp_l = flat >> 6;
        int n_l  = flat & 63;
        float2 v = make_float2(tile[n_l][2*dp_l], tile[n_l][2*dp_l + 1]);
        outp[((size_t)(d0/2 + dp_l) * Bsz + b) * (size_t)Nrows + n0 + n_l] = v;
    }
}

// ---------- unpack: (dp, b, n) float2 -> (b,n,d) f32 ----------
__global__ __launch_bounds__(256) void unpack_kernel(const float2* __restrict__ in,
                                                     float* __restrict__ outp) {
    __shared__ float tile[64][65];
    int tid = threadIdx.x;
    int n0 = blockIdx.x * 64;
    int d0 = blockIdx.y * 64;
    int b  = blockIdx.z;
    #pragma unroll
    for (int it = 0; it < 8; ++it) {
        int flat = it * 256 + tid;
        int dp_l = flat >> 6;
        int n_l  = flat & 63;
        float2 v = in[((size_t)(d0/2 + dp_l) * BATCH + b) * (size_t)NSEQ + n0 + n_l];
        tile[n_l][2*dp_l]     = v.x;
        tile[n_l][2*dp_l + 1] = v.y;
    }
    __syncthreads();
    float* ob = outp + (size_t)b * NSEQ * D;
    #pragma unroll
    for (int it = 0; it < 16; ++it) {
        int n_l = it * 4 + (tid >> 6);
        int d_l = tid & 63;
        ob[(size_t)(n0 + n_l) * D + d0 + d_l] = tile[n_l][d_l];
    }
}

extern "C" void kernel_launch(void* const* d_in, const int* in_sizes, int n_in,
                              void* d_out, int out_size, void* d_ws, size_t ws_size,
                              hipStream_t stream) {
    const float* x = (const float*)d_in[0];   // (4, 4096, 1024) f32
    const float* t = (const float*)d_in[1];   // (8192, 1024) f32
    float* outp = (float*)d_out;              // (4, 4096, 1024) f32

    char* ws = (char*)d_ws;
    float2* wtab   = (float2*)ws;                                   // 32 KB used, 64 KB reserved
    float4* tspecU = (float4*)(ws + 65536);                         // 512*4097*16 = 33,562,624
    const size_t OFF_XP = 65536 + (size_t)NDP * TSLOT * 16;         // 33,628,160
    float2* xP = (float2*)(ws + OFF_XP);                            // 64 MB
    const size_t need_full = OFF_XP + (size_t)NDP * BATCH * NSEQ * sizeof(float2);

    wtab_init<<<16, 256, 0, stream>>>(wtab);

    if (ws_size >= need_full) {
        tspec_kernel<<<NDP, NT, 0, stream>>>(t, wtab, tspecU);        // strided read, no pack_t
        pack_kernel<<<dim3(64, 16, BATCH), 256, 0, stream>>>(x, xP, NSEQ, BATCH);
        conv_kernel_p<<<dim3(NDP, BATCH, 1), NT, 0, stream>>>(xP, wtab, tspecU);
        unpack_kernel<<<dim3(64, 16, BATCH), 256, 0, stream>>>(xP, outp);
    } else {
        tspec_kernel<<<NDP, NT, 0, stream>>>(t, wtab, tspecU);
        conv_kernel_s<<<NDP * BATCH, NT, 0, stream>>>(x, outp, wtab, tspecU);
    }
}

// Round 12
// 188.265 us; speedup vs baseline: 1.0387x; 1.0387x over previous
//
#include <hip/hip_runtime.h>
#include <hip/hip_bf16.h>

#define NFFT 8192
#define NH   4096
#define D    1024
#define NSEQ 4096
#define NDP  512
#define BATCH 4
#define NT   512
#define TSLOT 4097
#define PI_D 3.14159265358979323846

// 16-pt DFT internal constants
#define C1 0.92387953251128675613f
#define S1 0.38268343236508977173f
#define RT 0.70710678118654752440f

__device__ __forceinline__ int SWZ(int i) { return i ^ ((i >> 4) & 15) ^ ((i >> 8) & 15); }

__device__ __forceinline__ float2 cadd(float2 a, float2 b){ return make_float2(a.x+b.x, a.y+b.y); }
__device__ __forceinline__ float2 csub(float2 a, float2 b){ return make_float2(a.x-b.x, a.y-b.y); }
__device__ __forceinline__ float2 cmul(float2 a, float2 w){ return make_float2(a.x*w.x - a.y*w.y, a.x*w.y + a.y*w.x); }
__device__ __forceinline__ float2 cmulc(float2 a, float2 w){ return make_float2(a.x*w.x + a.y*w.y, a.y*w.x - a.x*w.y); }

// digit-reversal for radices [2,16,16,16] DIF (radix-2 first, stride 4096)
__device__ __forceinline__ int drev16(int k) {
    return ((k & 1) << 12) | (((k >> 1) & 15) << 8) | (((k >> 5) & 15) << 4) | ((k >> 9) & 15);
}
// bank-aware bijection tid(9b) x it(3b) -> k in [0,4096)
__device__ __forceinline__ int kmap16(int tid, int it) {
    return ((tid >> 7) & 3) | (it << 2) | ((tid & 15) << 5) | (((tid >> 4) & 7) << 9);
}

__global__ __launch_bounds__(256) void wtab_init(float2* __restrict__ wtab) {
    int m = blockIdx.x * 256 + threadIdx.x;   // grid 16 -> 4096 entries
    double a = -2.0 * PI_D * (double)m / (double)NFFT;
    wtab[m] = make_float2((float)cos(a), (float)sin(a));
}

// One radix-16 pass over LDS. Thread owns 16 points at stride H within its group.
template<int H, bool TW, bool INV>
__device__ __forceinline__ void pass16(float2* zs, const float2* __restrict__ wt, int t) {
    int blk = t >> 8;
    int i0, tw1i;
    if (H == 256)      { int j = t & 255;                      i0 = blk*4096 + j;           tw1i = 2*j;  }
    else if (H == 16)  { int g = (t>>4) & 15; int j = t & 15;  i0 = blk*4096 + g*256 + j;   tw1i = 32*j; }
    else               { int g = t & 255;                      i0 = blk*4096 + g*16;        tw1i = 0;    }

    float2 w1, w2, w3, w4, w8, w12;
    if (TW) {
        w1 = wt[tw1i];
        w2 = cmul(w1, w1);  w3 = cmul(w2, w1);
        w4 = cmul(w2, w2);  w8 = cmul(w4, w4);  w12 = cmul(w8, w4);
    }

    float2 v[16];
    #pragma unroll
    for (int q = 0; q < 16; ++q) v[q] = zs[SWZ(i0 + H*q)];

    if (INV && TW) {
        v[1]=cmulc(v[1],w1);  v[2]=cmulc(v[2],w2);  v[3]=cmulc(v[3],w3);
        v[4]=cmulc(v[4],w4);  v[5]=cmulc(v[5],cmul(w4,w1));  v[6]=cmulc(v[6],cmul(w4,w2));  v[7]=cmulc(v[7],cmul(w4,w3));
        v[8]=cmulc(v[8],w8);  v[9]=cmulc(v[9],cmul(w8,w1));  v[10]=cmulc(v[10],cmul(w8,w2)); v[11]=cmulc(v[11],cmul(w8,w3));
        v[12]=cmulc(v[12],w12); v[13]=cmulc(v[13],cmul(w12,w1)); v[14]=cmulc(v[14],cmul(w12,w2)); v[15]=cmulc(v[15],cmul(w12,w3));
    }

    // layer 1
    float2 s[4][4];
    #pragma unroll
    for (int i = 0; i < 4; ++i) {
        float2 z0=v[i], z1=v[i+4], z2=v[i+8], z3=v[i+12];
        float2 A=cadd(z0,z2), Cc=csub(z0,z2), B=cadd(z1,z3), Dd=csub(z1,z3);
        s[i][0] = cadd(A,B);
        s[i][2] = csub(A,B);
        if (!INV) { s[i][1] = make_float2(Cc.x+Dd.y, Cc.y-Dd.x);
                    s[i][3] = make_float2(Cc.x-Dd.y, Cc.y+Dd.x); }
        else      { s[i][1] = make_float2(Cc.x-Dd.y, Cc.y+Dd.x);
                    s[i][3] = make_float2(Cc.x+Dd.y, Cc.y-Dd.x); }
    }
    // internal twiddles W16^{i*o} (conj for INV)
    if (!INV) {
        s[1][1]=cmul(s[1][1],make_float2(C1,-S1)); s[1][2]=cmul(s[1][2],make_float2(RT,-RT)); s[1][3]=cmul(s[1][3],make_float2(S1,-C1));
        s[2][1]=cmul(s[2][1],make_float2(RT,-RT)); s[2][2]=make_float2(s[2][2].y,-s[2][2].x); s[2][3]=cmul(s[2][3],make_float2(-RT,-RT));
        s[3][1]=cmul(s[3][1],make_float2(S1,-C1)); s[3][2]=cmul(s[3][2],make_float2(-RT,-RT)); s[3][3]=cmul(s[3][3],make_float2(-C1,S1));
    } else {
        s[1][1]=cmul(s[1][1],make_float2(C1,S1));  s[1][2]=cmul(s[1][2],make_float2(RT,RT));  s[1][3]=cmul(s[1][3],make_float2(S1,C1));
        s[2][1]=cmul(s[2][1],make_float2(RT,RT));  s[2][2]=make_float2(-s[2][2].y,s[2][2].x); s[2][3]=cmul(s[2][3],make_float2(-RT,RT));
        s[3][1]=cmul(s[3][1],make_float2(S1,C1));  s[3][2]=cmul(s[3][2],make_float2(-RT,RT)); s[3][3]=cmul(s[3][3],make_float2(-C1,-S1));
    }
    // layer 2
    float2 y[16];
    #pragma unroll
    for (int o = 0; o < 4; ++o) {
        float2 z0=s[0][o], z1=s[1][o], z2=s[2][o], z3=s[3][o];
        float2 A=cadd(z0,z2), Cc=csub(z0,z2), B=cadd(z1,z3), Dd=csub(z1,z3);
        y[o]    = cadd(A,B);
        y[o+8]  = csub(A,B);
        if (!INV) { y[o+4]  = make_float2(Cc.x+Dd.y, Cc.y-Dd.x);
                    y[o+12] = make_float2(Cc.x-Dd.y, Cc.y+Dd.x); }
        else      { y[o+4]  = make_float2(Cc.x-Dd.y, Cc.y+Dd.x);
                    y[o+12] = make_float2(Cc.x+Dd.y, Cc.y-Dd.x); }
    }

    if (!INV && TW) {
        y[1]=cmul(y[1],w1);  y[2]=cmul(y[2],w2);  y[3]=cmul(y[3],w3);
        y[4]=cmul(y[4],w4);  y[5]=cmul(y[5],cmul(w4,w1));  y[6]=cmul(y[6],cmul(w4,w2));  y[7]=cmul(y[7],cmul(w4,w3));
        y[8]=cmul(y[8],w8);  y[9]=cmul(y[9],cmul(w8,w1));  y[10]=cmul(y[10],cmul(w8,w2)); y[11]=cmul(y[11],cmul(w8,w3));
        y[12]=cmul(y[12],w12); y[13]=cmul(y[13],cmul(w12,w1)); y[14]=cmul(y[14],cmul(w12,w2)); y[15]=cmul(y[15],cmul(w12,w3));
    }
    #pragma unroll
    for (int r = 0; r < 16; ++r) zs[SWZ(i0 + H*r)] = y[r];
}

// ---------- tspec: strided t read (XCD swizzle), fwd FFT, untangle -> slot-ordered T ----------
__global__ __launch_bounds__(NT, 2) void tspec_kernel(const float* __restrict__ tg,
                                                      const float2* __restrict__ wt,
                                                      float4* __restrict__ tspecU) {
    __shared__ float2 zs[NFFT];
    int wg = blockIdx.x;
    int dp = ((wg & 7) << 6) | (wg >> 3);   // bijective [0,512): 8 line-sharing blocks per XCD
    int t  = threadIdx.x;

    const float* tb = tg + 2 * dp;
    #pragma unroll
    for (int it = 0; it < 8; ++it) {
        int idx = t + it * NT;
        float2 v0 = *(const float2*)(tb + (size_t)idx * D);
        float2 v1 = *(const float2*)(tb + (size_t)(idx + NH) * D);
        zs[SWZ(idx)]      = cadd(v0, v1);
        zs[SWZ(idx + NH)] = cmul(csub(v0, v1), wt[idx]);
    }
    __syncthreads();
    pass16<256, true,  false>(zs, wt, t); __syncthreads();
    pass16<16,  true,  false>(zs, wt, t); __syncthreads();
    pass16<1,   false, false>(zs, wt, t); __syncthreads();

    float4* o = tspecU + (size_t)dp * TSLOT;
    #pragma unroll
    for (int it = 0; it < 8; ++it) {
        int k  = kmap16(t, it);
        int p1 = drev16(k);
        int p2 = drev16((NFFT - k) & (NFFT - 1));
        float2 z1 = zs[SWZ(p1)], z2 = zs[SWZ(p2)];
        o[it * NT + t] = make_float4(0.5f*(z1.x + z2.x), 0.5f*(z1.y - z2.y),
                                     0.5f*(z1.y + z2.y), 0.5f*(z2.x - z1.x));
    }
    if (t == 0) {   // Nyquist bin k=4096 at position drev16(4096)=8
        float2 zn = zs[SWZ(8)];
        o[4096] = make_float4(zn.x, 0.f, zn.y, 0.f);
    }
}

// ---------- conv: packed x read, STRIDED out write (XCD-swizzled 1D grid) ----------
// wg -> xcd = wg&7, ix = wg>>3, b = ix>>6, dp = xcd*64 + (ix&63).
// The 8 dps sharing each 64B out-line have equal dp>>6 -> same XCD -> L2 write-combine.
// T loads at point of use (round-11 showed prefetch hurts the staging critical path).
template<int PACKED>
__global__ __launch_bounds__(NT, 2) void conv_kernel(const float2* __restrict__ xP,
                                                     const float* __restrict__ xg,
                                                     float* __restrict__ outg,
                                                     const float2* __restrict__ wt,
                                                     const float4* __restrict__ tspecU) {
    __shared__ float2 zs[NFFT];
    int wg = blockIdx.x;
    int xcd = wg & 7, ix = wg >> 3;
    int b  = ix >> 6;
    int dp = (xcd << 6) | (ix & 63);
    int t  = threadIdx.x;

    // load + fused first radix-2 (upper half is zero padding)
    if (PACKED) {
        const float2* slab = xP + ((size_t)dp * BATCH + b) * NSEQ;
        #pragma unroll
        for (int it = 0; it < 8; ++it) {
            int idx = t + it * NT;
            float2 v = slab[idx];
            zs[SWZ(idx)]      = v;                     // x + 0
            zs[SWZ(idx + NH)] = cmul(v, wt[idx]);      // (x - 0)*W^idx
        }
    } else {
        const float* xb = xg + (size_t)b * NSEQ * D + 2 * dp;
        #pragma unroll
        for (int it = 0; it < 8; ++it) {
            int idx = t + it * NT;
            float2 v = *(const float2*)(xb + (size_t)idx * D);
            zs[SWZ(idx)]      = v;
            zs[SWZ(idx + NH)] = cmul(v, wt[idx]);
        }
    }
    __syncthreads();
    pass16<256, true,  false>(zs, wt, t); __syncthreads();
    pass16<16,  true,  false>(zs, wt, t); __syncthreads();
    pass16<1,   false, false>(zs, wt, t); __syncthreads();

    // untangle * multiply * repack (T streamed slot-ordered, coalesced, at point of use)
    const float4* ts4 = tspecU + (size_t)dp * TSLOT;
    #pragma unroll
    for (int it = 0; it < 8; ++it) {
        int k  = kmap16(t, it);
        int p1 = drev16(k);
        int p2 = drev16((NFFT - k) & (NFFT - 1));
        float2 z1 = zs[SWZ(p1)], z2 = zs[SWZ(p2)];
        float4 T  = ts4[it * NT + t];
        float x0r = 0.5f*(z1.x + z2.x), x0i = 0.5f*(z1.y - z2.y);
        float x1r = 0.5f*(z1.y + z2.y), x1i = 0.5f*(z2.x - z1.x);
        float y0r = x0r*T.x - x0i*T.y, y0i = x0r*T.y + x0i*T.x;
        float y1r = x1r*T.z - x1i*T.w, y1i = x1r*T.w + x1i*T.z;
        zs[SWZ(p1)] = make_float2(y0r - y1i, y0i + y1r);
        zs[SWZ(p2)] = make_float2(y0r + y1i, y1r - y0i);
    }
    if (t == 0) {
        float4 T = ts4[4096];
        float2 zn = zs[SWZ(8)];
        zs[SWZ(8)] = make_float2(zn.x * T.x, zn.y * T.z);
    }
    __syncthreads();

    pass16<1,   false, true>(zs, wt, t); __syncthreads();
    pass16<16,  true,  true>(zs, wt, t); __syncthreads();
    pass16<256, true,  true>(zs, wt, t); __syncthreads();

    // final radix-2 (only n < 4096 needed) fused with STRIDED store to out
    const float sc = 1.0f / (float)NFFT;
    float* ob = outg + (size_t)b * NSEQ * D + 2 * dp;
    #pragma unroll
    for (int it = 0; it < 8; ++it) {
        int n = t + it * NT;
        float2 a  = zs[SWZ(n)];
        float2 bb = zs[SWZ(n + NH)];
        float2 r  = cadd(a, cmulc(bb, wt[n]));
        *(float2*)(ob + (size_t)n * D) = make_float2(r.x * sc, r.y * sc);
    }
}

// ---------- transpose/pack: (b,n,d) f32 -> (dp, b, n) float2 ----------
__global__ __launch_bounds__(256) void pack_kernel(const float* __restrict__ in,
                                                   float2* __restrict__ outp,
                                                   int Nrows, int Bsz) {
    __shared__ float tile[64][65];
    int tid = threadIdx.x;
    int n0 = blockIdx.x * 64;
    int d0 = blockIdx.y * 64;
    int b  = blockIdx.z;
    const float* ib = in + (size_t)b * Nrows * D;
    #pragma unroll
    for (int it = 0; it < 16; ++it) {
        int n_l = it * 4 + (tid >> 6);
        int d_l = tid & 63;
        tile[n_l][d_l] = ib[(size_t)(n0 + n_l) * D + d0 + d_l];
    }
    __syncthreads();
    #pragma unroll
    for (int it = 0; it < 8; ++it) {
        int flat = it * 256 + tid;
        int dp_l = flat >> 6;
        int n_l  = flat & 63;
        float2 v = make_float2(tile[n_l][2*dp_l], tile[n_l][2*dp_l + 1]);
        outp[((size_t)(d0/2 + dp_l) * Bsz + b) * (size_t)Nrows + n0 + n_l] = v;
    }
}

extern "C" void kernel_launch(void* const* d_in, const int* in_sizes, int n_in,
                              void* d_out, int out_size, void* d_ws, size_t ws_size,
                              hipStream_t stream) {
    const float* x = (const float*)d_in[0];   // (4, 4096, 1024) f32
    const float* t = (const float*)d_in[1];   // (8192, 1024) f32
    float* outp = (float*)d_out;              // (4, 4096, 1024) f32

    char* ws = (char*)d_ws;
    float2* wtab   = (float2*)ws;                                   // 32 KB used, 64 KB reserved
    float4* tspecU = (float4*)(ws + 65536);                         // 512*4097*16 = 33,562,624
    const size_t OFF_XP = 65536 + (size_t)NDP * TSLOT * 16;         // 33,628,160
    float2* xP = (float2*)(ws + OFF_XP);                            // 64 MB
    const size_t need_full = OFF_XP + (size_t)NDP * BATCH * NSEQ * sizeof(float2);

    wtab_init<<<16, 256, 0, stream>>>(wtab);
    tspec_kernel<<<NDP, NT, 0, stream>>>(t, wtab, tspecU);          // strided read, no pack_t

    if (ws_size >= need_full) {
        pack_kernel<<<dim3(64, 16, BATCH), 256, 0, stream>>>(x, xP, NSEQ, BATCH);
        conv_kernel<1><<<NDP * BATCH, NT, 0, stream>>>(xP, nullptr, outp, wtab, tspecU);
    } else {
        conv_kernel<0><<<NDP * BATCH, NT, 0, stream>>>(nullptr, x, outp, wtab, tspecU);
    }
}

// Round 13
// 167.278 us; speedup vs baseline: 1.1690x; 1.1255x over previous
//
#include <hip/hip_runtime.h>
#include <hip/hip_bf16.h>

#define NFFT 8192
#define NH   4096
#define D    1024
#define NSEQ 4096
#define NDP  512
#define BATCH 4
#define NT   512
#define PI_D 3.14159265358979323846

// 16-pt DFT internal constants
#define C1 0.92387953251128675613f
#define S1 0.38268343236508977173f
#define RT 0.70710678118654752440f

__device__ __forceinline__ int SWZ(int i) { return i ^ ((i >> 4) & 15) ^ ((i >> 8) & 15); }

__device__ __forceinline__ float2 cadd(float2 a, float2 b){ return make_float2(a.x+b.x, a.y+b.y); }
__device__ __forceinline__ float2 csub(float2 a, float2 b){ return make_float2(a.x-b.x, a.y-b.y); }
__device__ __forceinline__ float2 cmul(float2 a, float2 w){ return make_float2(a.x*w.x - a.y*w.y, a.x*w.y + a.y*w.x); }
__device__ __forceinline__ float2 cmulc(float2 a, float2 w){ return make_float2(a.x*w.x + a.y*w.y, a.y*w.x - a.x*w.y); }

// digit-reversal for radices [2,16,16,16] DIF on 8192 (tspec)
__device__ __forceinline__ int drev16(int k) {
    return ((k & 1) << 12) | (((k >> 1) & 15) << 8) | (((k >> 5) & 15) << 4) | ((k >> 9) & 15);
}
// bank-aware bijection tid(9b) x it(3b) -> k in [0,4096)  (tspec)
__device__ __forceinline__ int kmap16(int tid, int it) {
    return ((tid >> 7) & 3) | (it << 2) | ((tid & 15) << 5) | (((tid >> 4) & 7) << 9);
}
// digit-reversal for radices [16,16,16] DIF on 4096 (conv) — equals per-half of drev16
__device__ __forceinline__ int drev12(int k) {
    return ((k & 15) << 8) | (((k >> 4) & 15) << 4) | ((k >> 8) & 15);
}

__global__ __launch_bounds__(256) void wtab_init(float2* __restrict__ wtab) {
    int m = blockIdx.x * 256 + threadIdx.x;   // grid 16 -> 4096 entries: W8192^m
    double a = -2.0 * PI_D * (double)m / (double)NFFT;
    wtab[m] = make_float2((float)cos(a), (float)sin(a));
}

// in-register 16-pt DFT (DIF layers), in-place on v[16]
template<bool INV>
__device__ __forceinline__ void dft16(float2 v[16]) {
    float2 s[4][4];
    #pragma unroll
    for (int i = 0; i < 4; ++i) {
        float2 z0=v[i], z1=v[i+4], z2=v[i+8], z3=v[i+12];
        float2 A=cadd(z0,z2), Cc=csub(z0,z2), B=cadd(z1,z3), Dd=csub(z1,z3);
        s[i][0] = cadd(A,B);
        s[i][2] = csub(A,B);
        if (!INV) { s[i][1] = make_float2(Cc.x+Dd.y, Cc.y-Dd.x);
                    s[i][3] = make_float2(Cc.x-Dd.y, Cc.y+Dd.x); }
        else      { s[i][1] = make_float2(Cc.x-Dd.y, Cc.y+Dd.x);
                    s[i][3] = make_float2(Cc.x+Dd.y, Cc.y-Dd.x); }
    }
    if (!INV) {
        s[1][1]=cmul(s[1][1],make_float2(C1,-S1)); s[1][2]=cmul(s[1][2],make_float2(RT,-RT)); s[1][3]=cmul(s[1][3],make_float2(S1,-C1));
        s[2][1]=cmul(s[2][1],make_float2(RT,-RT)); s[2][2]=make_float2(s[2][2].y,-s[2][2].x); s[2][3]=cmul(s[2][3],make_float2(-RT,-RT));
        s[3][1]=cmul(s[3][1],make_float2(S1,-C1)); s[3][2]=cmul(s[3][2],make_float2(-RT,-RT)); s[3][3]=cmul(s[3][3],make_float2(-C1,S1));
    } else {
        s[1][1]=cmul(s[1][1],make_float2(C1,S1));  s[1][2]=cmul(s[1][2],make_float2(RT,RT));  s[1][3]=cmul(s[1][3],make_float2(S1,C1));
        s[2][1]=cmul(s[2][1],make_float2(RT,RT));  s[2][2]=make_float2(-s[2][2].y,s[2][2].x); s[2][3]=cmul(s[2][3],make_float2(-RT,RT));
        s[3][1]=cmul(s[3][1],make_float2(S1,C1));  s[3][2]=cmul(s[3][2],make_float2(-RT,RT)); s[3][3]=cmul(s[3][3],make_float2(-C1,-S1));
    }
    #pragma unroll
    for (int o = 0; o < 4; ++o) {
        float2 z0=s[0][o], z1=s[1][o], z2=s[2][o], z3=s[3][o];
        float2 A=cadd(z0,z2), Cc=csub(z0,z2), B=cadd(z1,z3), Dd=csub(z1,z3);
        v[o]    = cadd(A,B);
        v[o+8]  = csub(A,B);
        if (!INV) { v[o+4]  = make_float2(Cc.x+Dd.y, Cc.y-Dd.x);
                    v[o+12] = make_float2(Cc.x-Dd.y, Cc.y+Dd.x); }
        else      { v[o+4]  = make_float2(Cc.x-Dd.y, Cc.y+Dd.x);
                    v[o+12] = make_float2(Cc.x+Dd.y, Cc.y-Dd.x); }
    }
}

__device__ __forceinline__ void twiddle_fwd(float2 v[16], const float2* __restrict__ wt, int tw1i) {
    float2 w1 = wt[tw1i];
    float2 w2 = cmul(w1,w1), w3 = cmul(w2,w1), w4 = cmul(w2,w2), w8 = cmul(w4,w4), w12 = cmul(w8,w4);
    v[1]=cmul(v[1],w1);  v[2]=cmul(v[2],w2);  v[3]=cmul(v[3],w3);
    v[4]=cmul(v[4],w4);  v[5]=cmul(v[5],cmul(w4,w1));  v[6]=cmul(v[6],cmul(w4,w2));  v[7]=cmul(v[7],cmul(w4,w3));
    v[8]=cmul(v[8],w8);  v[9]=cmul(v[9],cmul(w8,w1));  v[10]=cmul(v[10],cmul(w8,w2)); v[11]=cmul(v[11],cmul(w8,w3));
    v[12]=cmul(v[12],w12); v[13]=cmul(v[13],cmul(w12,w1)); v[14]=cmul(v[14],cmul(w12,w2)); v[15]=cmul(v[15],cmul(w12,w3));
}
__device__ __forceinline__ void twiddle_inv(float2 v[16], const float2* __restrict__ wt, int tw1i) {
    float2 w1 = wt[tw1i];
    float2 w2 = cmul(w1,w1), w3 = cmul(w2,w1), w4 = cmul(w2,w2), w8 = cmul(w4,w4), w12 = cmul(w8,w4);
    v[1]=cmulc(v[1],w1);  v[2]=cmulc(v[2],w2);  v[3]=cmulc(v[3],w3);
    v[4]=cmulc(v[4],w4);  v[5]=cmulc(v[5],cmul(w4,w1));  v[6]=cmulc(v[6],cmul(w4,w2));  v[7]=cmulc(v[7],cmul(w4,w3));
    v[8]=cmulc(v[8],w8);  v[9]=cmulc(v[9],cmul(w8,w1));  v[10]=cmulc(v[10],cmul(w8,w2)); v[11]=cmulc(v[11],cmul(w8,w3));
    v[12]=cmulc(v[12],w12); v[13]=cmulc(v[13],cmul(w12,w1)); v[14]=cmulc(v[14],cmul(w12,w2)); v[15]=cmulc(v[15],cmul(w12,w3));
}

// 8192 passes for tspec (NT=512, two 4096-halves)
template<int H, bool TW, bool INV>
__device__ __forceinline__ void pass16(float2* zs, const float2* __restrict__ wt, int t) {
    int blk = t >> 8;
    int i0, tw1i;
    if (H == 256)      { int j = t & 255;                      i0 = blk*4096 + j;           tw1i = 2*j;  }
    else if (H == 16)  { int g = (t>>4) & 15; int j = t & 15;  i0 = blk*4096 + g*256 + j;   tw1i = 32*j; }
    else               { int g = t & 255;                      i0 = blk*4096 + g*16;        tw1i = 0;    }
    float2 v[16];
    #pragma unroll
    for (int q = 0; q < 16; ++q) v[q] = zs[SWZ(i0 + H*q)];
    if (INV && TW) twiddle_inv(v, wt, tw1i);
    dft16<INV>(v);
    if (!INV && TW) twiddle_fwd(v, wt, tw1i);
    #pragma unroll
    for (int r = 0; r < 16; ++r) zs[SWZ(i0 + H*r)] = v[r];
}

// 4096 middle passes for conv (NT=256)
template<int H, bool TW, bool INV>
__device__ __forceinline__ void pass16q(float2* zs, const float2* __restrict__ wt, int t) {
    int i0, tw1i;
    if (H == 16) { int g = t >> 4, j = t & 15; i0 = g*256 + j; tw1i = 32*j; }
    else         { i0 = t*16; tw1i = 0; }
    float2 v[16];
    #pragma unroll
    for (int q = 0; q < 16; ++q) v[q] = zs[SWZ(i0 + H*q)];
    if (INV && TW) twiddle_inv(v, wt, tw1i);
    dft16<INV>(v);
    if (!INV && TW) twiddle_fwd(v, wt, tw1i);
    #pragma unroll
    for (int r = 0; r < 16; ++r) zs[SWZ(i0 + H*r)] = v[r];
}

// ---------- tspec: 8192-FFT per dp-pair (proven), output -> per-channel PAIRED slots ----------
// tsPall[c][lin] = float4( T[k].re, T[k].im, T[4096-k].re, T[4096-k].im ), lin = conv's
// enumeration order (it*256+t for k=smap(t,it)); slot 2048 appended for k=2048.
__global__ __launch_bounds__(NT, 2) void tspec_kernel(const float* __restrict__ tg,
                                                      const float2* __restrict__ wt,
                                                      float4* __restrict__ tsPall) {
    __shared__ float2 zs[NFFT];
    int wg = blockIdx.x;
    int dp = ((wg & 7) << 6) | (wg >> 3);   // XCD swizzle: 8 line-sharing blocks per XCD
    int t  = threadIdx.x;

    const float* tb = tg + 2 * dp;
    #pragma unroll
    for (int it = 0; it < 8; ++it) {
        int idx = t + it * NT;
        float2 v0 = *(const float2*)(tb + (size_t)idx * D);
        float2 v1 = *(const float2*)(tb + (size_t)(idx + NH) * D);
        zs[SWZ(idx)]      = cadd(v0, v1);
        zs[SWZ(idx + NH)] = cmul(csub(v0, v1), wt[idx]);
    }
    __syncthreads();
    pass16<256, true,  false>(zs, wt, t); __syncthreads();
    pass16<16,  true,  false>(zs, wt, t); __syncthreads();
    pass16<1,   false, false>(zs, wt, t); __syncthreads();

    #pragma unroll
    for (int it = 0; it < 8; ++it) {
        int k  = kmap16(t, it);
        int p1 = drev16(k);
        int p2 = drev16((NFFT - k) & (NFFT - 1));
        float2 z1 = zs[SWZ(p1)], z2 = zs[SWZ(p2)];
        float2 T0 = make_float2(0.5f*(z1.x + z2.x), 0.5f*(z1.y - z2.y));
        float2 T1 = make_float2(0.5f*(z1.y + z2.y), 0.5f*(z2.x - z1.x));
        int s   = (k <= 2048) ? k : (4096 - k);
        int lin = (s == 2048) ? 2048
                              : ((s & 7) * 256 + (((s >> 8) & 7) | (((s >> 3) & 31) << 3)));
        float2* w0 = (float2*)(tsPall + ((size_t)(2*dp)     * 2049 + lin));
        float2* w1 = (float2*)(tsPall + ((size_t)(2*dp + 1) * 2049 + lin));
        if (k < 2048)      { w0[0] = T0; w1[0] = T1; }
        else if (k > 2048) { w0[1] = T0; w1[1] = T1; }
        else               { w0[0] = T0; w0[1] = T0; w1[0] = T1; w1[1] = T1; }
    }
    if (t == 0) {   // Nyquist k=4096 (at drev16(4096)=8) -> slot 0 .zw
        float2 zn = zs[SWZ(8)];
        float2* w0 = (float2*)(tsPall + (size_t)(2*dp)     * 2049);
        float2* w1 = (float2*)(tsPall + (size_t)(2*dp + 1) * 2049);
        w0[1] = make_float2(zn.x, 0.f);
        w1[1] = make_float2(zn.y, 0.f);
    }
}

// One real-conv spectral pair (k, 4096-k): X=A+W·B / conj(A-W·B); Y=X·T; W=E+iO repack.
// Generic for ALL k in [0,2048] (k=0 and k=2048 double-write identical values — verified).
__device__ __forceinline__ void conv_pair(float2* zs, const float2* __restrict__ wt,
                                          float4 Tq, int k) {
    int p1 = drev12(k);
    int kp = (4096 - k) & 4095;
    int p2 = drev12(kp);
    float2 Zk = zs[SWZ(p1)], Zp = zs[SWZ(p2)];
    float2 w = wt[k];                                     // W8192^k
    float Ar = 0.5f*(Zk.x + Zp.x), Ai = 0.5f*(Zk.y - Zp.y);
    float Br = 0.5f*(Zk.y + Zp.y), Bi = 0.5f*(Zp.x - Zk.x);
    float2 WB = make_float2(w.x*Br - w.y*Bi, w.x*Bi + w.y*Br);
    float2 X1 = make_float2(Ar + WB.x, Ai + WB.y);        // X[k]
    float2 X2 = make_float2(Ar - WB.x, WB.y - Ai);        // X[4096-k] = conj(A - W·B)
    float2 Y1 = make_float2(X1.x*Tq.x - X1.y*Tq.y, X1.x*Tq.y + X1.y*Tq.x);
    float2 Y2 = make_float2(X2.x*Tq.z - X2.y*Tq.w, X2.x*Tq.w + X2.y*Tq.z);
    float Er = 0.5f*(Y1.x + Y2.x), Ei = 0.5f*(Y1.y - Y2.y);
    float Gr = 0.5f*(Y1.x - Y2.x), Gi = 0.5f*(Y1.y + Y2.y);
    float O1x = Gr*w.x + Gi*w.y, O1y = Gi*w.x - Gr*w.y;   // O1 = G*conj(w)
    float O2x = O1x,             O2y = Gr*w.y - Gi*w.x;   // O2 = conj(G)*w
    zs[SWZ(p1)] = make_float2(Er - O1y, Ei + O1x);        // W[k]      = E + i*O1
    zs[SWZ(p2)] = make_float2(Er - O2y, O2x - Ei);        // W[4096-k] = conj(E) + i*O2
}

// ---------- conv: per (channel c, batch b); even/odd-packed real-conv via FFT-4096 ----------
// 32KB LDS -> up to 5 blocks/CU (vs 2 at 64KB). xQ/oQ in-place slab (c,b).
template<int PACKED>
__global__ __launch_bounds__(256, 4) void conv_kernel(float* __restrict__ region,
                                                      const float* __restrict__ xg,
                                                      float* __restrict__ outg,
                                                      const float2* __restrict__ wt,
                                                      const float4* __restrict__ tsPall) {
    __shared__ float2 zs[4096];
    int wg  = blockIdx.x;
    int c   = (wg & 7) * 128 + ((wg >> 3) & 127);   // XCD swizzle: 128 contiguous c per XCD
    int b   = wg >> 10;
    int t   = threadIdx.x;

    float* slab = PACKED ? (region + ((size_t)c * BATCH + b) * NSEQ) : nullptr;

    // ---- fwd stage1 (H=256) fused with load: z[n] = x[2n] + i*x[2n+1], zero-padded
    {
        float2 v[16];
        #pragma unroll
        for (int q = 0; q < 8; ++q) {
            int n = t + 256*q;
            if (PACKED) v[q] = *(const float2*)(slab + 2*n);
            else {
                const float* xb = xg + (size_t)b * NSEQ * D + c;
                v[q] = make_float2(xb[(size_t)(2*n) * D], xb[(size_t)(2*n+1) * D]);
            }
        }
        #pragma unroll
        for (int q = 8; q < 16; ++q) v[q] = make_float2(0.f, 0.f);
        dft16<false>(v);
        twiddle_fwd(v, wt, 2*t);
        #pragma unroll
        for (int r = 0; r < 16; ++r) zs[SWZ(t + 256*r)] = v[r];
    }
    __syncthreads();
    pass16q<16, true,  false>(zs, wt, t); __syncthreads();
    pass16q<1,  false, false>(zs, wt, t); __syncthreads();

    // ---- untangle * T * repack (T slot-ordered coalesced; pairs race-free)
    const float4* tsP = tsPall + (size_t)c * 2049;
    #pragma unroll
    for (int it = 0; it < 8; ++it) {
        int k = ((t & 7) << 8) | ((t >> 3) << 3) | it;
        conv_pair(zs, wt, tsP[it * 256 + t], k);
    }
    if (t == 0) conv_pair(zs, wt, tsP[2048], 2048);
    __syncthreads();

    pass16q<1,  false, true>(zs, wt, t); __syncthreads();
    pass16q<16, true,  true>(zs, wt, t); __syncthreads();

    // ---- inv stage (H=256) fused with store: w[n] = y[2n] + i*y[2n+1]; keep n < 2048 only
    {
        float2 v[16];
        #pragma unroll
        for (int q = 0; q < 16; ++q) v[q] = zs[SWZ(t + 256*q)];
        twiddle_inv(v, wt, 2*t);
        dft16<true>(v);
        const float sc = 1.0f / 4096.0f;
        #pragma unroll
        for (int r = 0; r < 8; ++r) {
            int n = t + 256*r;
            float2 rv = make_float2(v[r].x * sc, v[r].y * sc);
            if (PACKED) *(float2*)(slab + 2*n) = rv;
            else {
                float* ob = outg + (size_t)b * NSEQ * D + c;
                ob[(size_t)(2*n) * D]   = rv.x;
                ob[(size_t)(2*n+1) * D] = rv.y;
            }
        }
    }
}

// ---------- pack: x(b,n,d) -> xQ[c][b][n] (deinterleaved channel-major) ----------
__global__ __launch_bounds__(256) void pack_xQ(const float* __restrict__ in,
                                               float* __restrict__ q) {
    __shared__ float tile[64][65];
    int tid = threadIdx.x;
    int n0 = blockIdx.x * 64, d0 = blockIdx.y * 64, b = blockIdx.z;
    const float* ib = in + (size_t)b * NSEQ * D;
    #pragma unroll
    for (int it = 0; it < 16; ++it) {
        int n_l = it * 4 + (tid >> 6);
        int d_l = tid & 63;
        tile[n_l][d_l] = ib[(size_t)(n0 + n_l) * D + d0 + d_l];
    }
    __syncthreads();
    #pragma unroll
    for (int it = 0; it < 16; ++it) {
        int flat = it * 256 + tid;
        int c_l = flat >> 6;
        int n_l = flat & 63;
        q[((size_t)(d0 + c_l) * BATCH + b) * NSEQ + n0 + n_l] = tile[n_l][c_l];
    }
}

// ---------- unpack: oQ[c][b][n] -> out(b,n,d) ----------
__global__ __launch_bounds__(256) void unpack_Q(const float* __restrict__ q,
                                                float* __restrict__ outp) {
    __shared__ float tile[64][65];
    int tid = threadIdx.x;
    int n0 = blockIdx.x * 64, d0 = blockIdx.y * 64, b = blockIdx.z;
    #pragma unroll
    for (int it = 0; it < 16; ++it) {
        int flat = it * 256 + tid;
        int c_l = flat >> 6;
        int n_l = flat & 63;
        tile[c_l][n_l] = q[((size_t)(d0 + c_l) * BATCH + b) * NSEQ + n0 + n_l];
    }
    __syncthreads();
    float* ob = outp + (size_t)b * NSEQ * D;
    #pragma unroll
    for (int it = 0; it < 16; ++it) {
        int n_l = it * 4 + (tid >> 6);
        int d_l = tid & 63;
        ob[(size_t)(n0 + n_l) * D + d0 + d_l] = tile[d_l][n_l];
    }
}

extern "C" void kernel_launch(void* const* d_in, const int* in_sizes, int n_in,
                              void* d_out, int out_size, void* d_ws, size_t ws_size,
                              hipStream_t stream) {
    const float* x = (const float*)d_in[0];   // (4, 4096, 1024) f32
    const float* t = (const float*)d_in[1];   // (8192, 1024) f32
    float* outp = (float*)d_out;              // (4, 4096, 1024) f32

    char* ws = (char*)d_ws;
    float2* wtab  = (float2*)ws;                                    // 32 KB used, 64 KB reserved
    float4* tsPall = (float4*)(ws + 65536);                         // 1024*2049*16 = 33,570,816
    const size_t OFF_Q = 65536 + (size_t)1024 * 2049 * 16;
    float* region = (float*)(ws + OFF_Q);                           // xQ/oQ in-place: 64 MB
    const size_t need_full = OFF_Q + (size_t)1024 * BATCH * NSEQ * sizeof(float); // ~96.1 MB

    wtab_init<<<16, 256, 0, stream>>>(wtab);
    tspec_kernel<<<NDP, NT, 0, stream>>>(t, wtab, tsPall);

    if (ws_size >= need_full) {
        pack_xQ<<<dim3(64, 16, BATCH), 256, 0, stream>>>(x, region);
        conv_kernel<1><<<1024 * BATCH, 256, 0, stream>>>(region, nullptr, nullptr, wtab, tsPall);
        unpack_Q<<<dim3(64, 16, BATCH), 256, 0, stream>>>(region, outp);
    } else {
        conv_kernel<0><<<1024 * BATCH, 256, 0, stream>>>(nullptr, x, outp, wtab, tsPall);
    }
}

// Round 14
// 156.748 us; speedup vs baseline: 1.2475x; 1.0672x over previous
//
#include <hip/hip_runtime.h>
#include <hip/hip_bf16.h>

#define NFFT 8192
#define NH   4096
#define D    1024
#define NSEQ 4096
#define NDP  512
#define BATCH 4
#define NT   512
#define PI_D 3.14159265358979323846

// 16-pt DFT internal constants
#define C1 0.92387953251128675613f
#define S1 0.38268343236508977173f
#define RT 0.70710678118654752440f

__device__ __forceinline__ int SWZ(int i) { return i ^ ((i >> 4) & 15) ^ ((i >> 8) & 15); }

__device__ __forceinline__ float2 cadd(float2 a, float2 b){ return make_float2(a.x+b.x, a.y+b.y); }
__device__ __forceinline__ float2 csub(float2 a, float2 b){ return make_float2(a.x-b.x, a.y-b.y); }
__device__ __forceinline__ float2 cmul(float2 a, float2 w){ return make_float2(a.x*w.x - a.y*w.y, a.x*w.y + a.y*w.x); }
__device__ __forceinline__ float2 cmulc(float2 a, float2 w){ return make_float2(a.x*w.x + a.y*w.y, a.y*w.x - a.x*w.y); }

// digit-reversal for radices [2,16,16,16] DIF on 8192 (tspec)
__device__ __forceinline__ int drev16(int k) {
    return ((k & 1) << 12) | (((k >> 1) & 15) << 8) | (((k >> 5) & 15) << 4) | ((k >> 9) & 15);
}
// bank-aware bijection tid(9b) x it(3b) -> k in [0,4096)  (tspec)
__device__ __forceinline__ int kmap16(int tid, int it) {
    return ((tid >> 7) & 3) | (it << 2) | ((tid & 15) << 5) | (((tid >> 4) & 7) << 9);
}
// digit-reversal for radices [16,16,16] DIF on 4096 (conv) — equals per-half of drev16
__device__ __forceinline__ int drev12(int k) {
    return ((k & 15) << 8) | (((k >> 4) & 15) << 4) | ((k >> 8) & 15);
}

__global__ __launch_bounds__(256) void wtab_init(float2* __restrict__ wtab) {
    int m = blockIdx.x * 256 + threadIdx.x;   // grid 16 -> 4096 entries: W8192^m
    double a = -2.0 * PI_D * (double)m / (double)NFFT;
    wtab[m] = make_float2((float)cos(a), (float)sin(a));
}

// in-register 16-pt DFT (DIF layers), in-place on v[16]
template<bool INV>
__device__ __forceinline__ void dft16(float2 v[16]) {
    float2 s[4][4];
    #pragma unroll
    for (int i = 0; i < 4; ++i) {
        float2 z0=v[i], z1=v[i+4], z2=v[i+8], z3=v[i+12];
        float2 A=cadd(z0,z2), Cc=csub(z0,z2), B=cadd(z1,z3), Dd=csub(z1,z3);
        s[i][0] = cadd(A,B);
        s[i][2] = csub(A,B);
        if (!INV) { s[i][1] = make_float2(Cc.x+Dd.y, Cc.y-Dd.x);
                    s[i][3] = make_float2(Cc.x-Dd.y, Cc.y+Dd.x); }
        else      { s[i][1] = make_float2(Cc.x-Dd.y, Cc.y+Dd.x);
                    s[i][3] = make_float2(Cc.x+Dd.y, Cc.y-Dd.x); }
    }
    if (!INV) {
        s[1][1]=cmul(s[1][1],make_float2(C1,-S1)); s[1][2]=cmul(s[1][2],make_float2(RT,-RT)); s[1][3]=cmul(s[1][3],make_float2(S1,-C1));
        s[2][1]=cmul(s[2][1],make_float2(RT,-RT)); s[2][2]=make_float2(s[2][2].y,-s[2][2].x); s[2][3]=cmul(s[2][3],make_float2(-RT,-RT));
        s[3][1]=cmul(s[3][1],make_float2(S1,-C1)); s[3][2]=cmul(s[3][2],make_float2(-RT,-RT)); s[3][3]=cmul(s[3][3],make_float2(-C1,S1));
    } else {
        s[1][1]=cmul(s[1][1],make_float2(C1,S1));  s[1][2]=cmul(s[1][2],make_float2(RT,RT));  s[1][3]=cmul(s[1][3],make_float2(S1,C1));
        s[2][1]=cmul(s[2][1],make_float2(RT,RT));  s[2][2]=make_float2(-s[2][2].y,s[2][2].x); s[2][3]=cmul(s[2][3],make_float2(-RT,RT));
        s[3][1]=cmul(s[3][1],make_float2(S1,C1));  s[3][2]=cmul(s[3][2],make_float2(-RT,RT)); s[3][3]=cmul(s[3][3],make_float2(-C1,-S1));
    }
    #pragma unroll
    for (int o = 0; o < 4; ++o) {
        float2 z0=s[0][o], z1=s[1][o], z2=s[2][o], z3=s[3][o];
        float2 A=cadd(z0,z2), Cc=csub(z0,z2), B=cadd(z1,z3), Dd=csub(z1,z3);
        v[o]    = cadd(A,B);
        v[o+8]  = csub(A,B);
        if (!INV) { v[o+4]  = make_float2(Cc.x+Dd.y, Cc.y-Dd.x);
                    v[o+12] = make_float2(Cc.x-Dd.y, Cc.y+Dd.x); }
        else      { v[o+4]  = make_float2(Cc.x-Dd.y, Cc.y+Dd.x);
                    v[o+12] = make_float2(Cc.x+Dd.y, Cc.y-Dd.x); }
    }
}

__device__ __forceinline__ void twiddle_fwd(float2 v[16], const float2* __restrict__ wt, int tw1i) {
    float2 w1 = wt[tw1i];
    float2 w2 = cmul(w1,w1), w3 = cmul(w2,w1), w4 = cmul(w2,w2), w8 = cmul(w4,w4), w12 = cmul(w8,w4);
    v[1]=cmul(v[1],w1);  v[2]=cmul(v[2],w2);  v[3]=cmul(v[3],w3);
    v[4]=cmul(v[4],w4);  v[5]=cmul(v[5],cmul(w4,w1));  v[6]=cmul(v[6],cmul(w4,w2));  v[7]=cmul(v[7],cmul(w4,w3));
    v[8]=cmul(v[8],w8);  v[9]=cmul(v[9],cmul(w8,w1));  v[10]=cmul(v[10],cmul(w8,w2)); v[11]=cmul(v[11],cmul(w8,w3));
    v[12]=cmul(v[12],w12); v[13]=cmul(v[13],cmul(w12,w1)); v[14]=cmul(v[14],cmul(w12,w2)); v[15]=cmul(v[15],cmul(w12,w3));
}
__device__ __forceinline__ void twiddle_inv(float2 v[16], const float2* __restrict__ wt, int tw1i) {
    float2 w1 = wt[tw1i];
    float2 w2 = cmul(w1,w1), w3 = cmul(w2,w1), w4 = cmul(w2,w2), w8 = cmul(w4,w4), w12 = cmul(w8,w4);
    v[1]=cmulc(v[1],w1);  v[2]=cmulc(v[2],w2);  v[3]=cmulc(v[3],w3);
    v[4]=cmulc(v[4],w4);  v[5]=cmulc(v[5],cmul(w4,w1));  v[6]=cmulc(v[6],cmul(w4,w2));  v[7]=cmulc(v[7],cmul(w4,w3));
    v[8]=cmulc(v[8],w8);  v[9]=cmulc(v[9],cmul(w8,w1));  v[10]=cmulc(v[10],cmul(w8,w2)); v[11]=cmulc(v[11],cmul(w8,w3));
    v[12]=cmulc(v[12],w12); v[13]=cmulc(v[13],cmul(w12,w1)); v[14]=cmulc(v[14],cmul(w12,w2)); v[15]=cmulc(v[15],cmul(w12,w3));
}

// 8192 passes for tspec (NT=512, two 4096-halves)
template<int H, bool TW, bool INV>
__device__ __forceinline__ void pass16(float2* zs, const float2* __restrict__ wt, int t) {
    int blk = t >> 8;
    int i0, tw1i;
    if (H == 256)      { int j = t & 255;                      i0 = blk*4096 + j;           tw1i = 2*j;  }
    else if (H == 16)  { int g = (t>>4) & 15; int j = t & 15;  i0 = blk*4096 + g*256 + j;   tw1i = 32*j; }
    else               { int g = t & 255;                      i0 = blk*4096 + g*16;        tw1i = 0;    }
    float2 v[16];
    #pragma unroll
    for (int q = 0; q < 16; ++q) v[q] = zs[SWZ(i0 + H*q)];
    if (INV && TW) twiddle_inv(v, wt, tw1i);
    dft16<INV>(v);
    if (!INV && TW) twiddle_fwd(v, wt, tw1i);
    #pragma unroll
    for (int r = 0; r < 16; ++r) zs[SWZ(i0 + H*r)] = v[r];
}

// 4096 middle passes for conv (NT=256)
template<int H, bool TW, bool INV>
__device__ __forceinline__ void pass16q(float2* zs, const float2* __restrict__ wt, int t) {
    int i0, tw1i;
    if (H == 16) { int g = t >> 4, j = t & 15; i0 = g*256 + j; tw1i = 32*j; }
    else         { i0 = t*16; tw1i = 0; }
    float2 v[16];
    #pragma unroll
    for (int q = 0; q < 16; ++q) v[q] = zs[SWZ(i0 + H*q)];
    if (INV && TW) twiddle_inv(v, wt, tw1i);
    dft16<INV>(v);
    if (!INV && TW) twiddle_fwd(v, wt, tw1i);
    #pragma unroll
    for (int r = 0; r < 16; ++r) zs[SWZ(i0 + H*r)] = v[r];
}

// ---------- tspec: 8192-FFT per dp-pair (proven), output -> per-channel PAIRED slots ----------
// tsPall[c][lin] = float4( T[k].re, T[k].im, T[4096-k].re, T[4096-k].im ), lin = conv's
// enumeration order (it*256+t for k=smap(t,it)); slot 2048 appended for k=2048.
__global__ __launch_bounds__(NT, 2) void tspec_kernel(const float* __restrict__ tg,
                                                      const float2* __restrict__ wt,
                                                      float4* __restrict__ tsPall) {
    __shared__ float2 zs[NFFT];
    int wg = blockIdx.x;
    int dp = ((wg & 7) << 6) | (wg >> 3);   // XCD swizzle: 8 line-sharing blocks per XCD
    int t  = threadIdx.x;

    const float* tb = tg + 2 * dp;
    #pragma unroll
    for (int it = 0; it < 8; ++it) {
        int idx = t + it * NT;
        float2 v0 = *(const float2*)(tb + (size_t)idx * D);
        float2 v1 = *(const float2*)(tb + (size_t)(idx + NH) * D);
        zs[SWZ(idx)]      = cadd(v0, v1);
        zs[SWZ(idx + NH)] = cmul(csub(v0, v1), wt[idx]);
    }
    __syncthreads();
    pass16<256, true,  false>(zs, wt, t); __syncthreads();
    pass16<16,  true,  false>(zs, wt, t); __syncthreads();
    pass16<1,   false, false>(zs, wt, t); __syncthreads();

    #pragma unroll
    for (int it = 0; it < 8; ++it) {
        int k  = kmap16(t, it);
        int p1 = drev16(k);
        int p2 = drev16((NFFT - k) & (NFFT - 1));
        float2 z1 = zs[SWZ(p1)], z2 = zs[SWZ(p2)];
        float2 T0 = make_float2(0.5f*(z1.x + z2.x), 0.5f*(z1.y - z2.y));
        float2 T1 = make_float2(0.5f*(z1.y + z2.y), 0.5f*(z2.x - z1.x));
        int s   = (k <= 2048) ? k : (4096 - k);
        int lin = (s == 2048) ? 2048
                              : ((s & 7) * 256 + (((s >> 8) & 7) | (((s >> 3) & 31) << 3)));
        float2* w0 = (float2*)(tsPall + ((size_t)(2*dp)     * 2049 + lin));
        float2* w1 = (float2*)(tsPall + ((size_t)(2*dp + 1) * 2049 + lin));
        if (k < 2048)      { w0[0] = T0; w1[0] = T1; }
        else if (k > 2048) { w0[1] = T0; w1[1] = T1; }
        else               { w0[0] = T0; w0[1] = T0; w1[0] = T1; w1[1] = T1; }
    }
    if (t == 0) {   // Nyquist k=4096 (at drev16(4096)=8) -> slot 0 .zw
        float2 zn = zs[SWZ(8)];
        float2* w0 = (float2*)(tsPall + (size_t)(2*dp)     * 2049);
        float2* w1 = (float2*)(tsPall + (size_t)(2*dp + 1) * 2049);
        w0[1] = make_float2(zn.x, 0.f);
        w1[1] = make_float2(zn.y, 0.f);
    }
}

// One real-conv spectral pair (k, 4096-k): X=A+W·B / conj(A-W·B); Y=X·T; W=E+iO repack.
// Generic for ALL k in [0,2048] (k=0 and k=2048 double-write identical values — verified).
__device__ __forceinline__ void conv_pair(float2* zs, const float2* __restrict__ wt,
                                          float4 Tq, int k) {
    int p1 = drev12(k);
    int kp = (4096 - k) & 4095;
    int p2 = drev12(kp);
    float2 Zk = zs[SWZ(p1)], Zp = zs[SWZ(p2)];
    float2 w = wt[k];                                     // W8192^k
    float Ar = 0.5f*(Zk.x + Zp.x), Ai = 0.5f*(Zk.y - Zp.y);
    float Br = 0.5f*(Zk.y + Zp.y), Bi = 0.5f*(Zp.x - Zk.x);
    float2 WB = make_float2(w.x*Br - w.y*Bi, w.x*Bi + w.y*Br);
    float2 X1 = make_float2(Ar + WB.x, Ai + WB.y);        // X[k]
    float2 X2 = make_float2(Ar - WB.x, WB.y - Ai);        // X[4096-k] = conj(A - W·B)
    float2 Y1 = make_float2(X1.x*Tq.x - X1.y*Tq.y, X1.x*Tq.y + X1.y*Tq.x);
    float2 Y2 = make_float2(X2.x*Tq.z - X2.y*Tq.w, X2.x*Tq.w + X2.y*Tq.z);
    float Er = 0.5f*(Y1.x + Y2.x), Ei = 0.5f*(Y1.y - Y2.y);
    float Gr = 0.5f*(Y1.x - Y2.x), Gi = 0.5f*(Y1.y + Y2.y);
    float O1x = Gr*w.x + Gi*w.y, O1y = Gi*w.x - Gr*w.y;   // O1 = G*conj(w)
    float O2x = O1x,             O2y = Gr*w.y - Gi*w.x;   // O2 = conj(G)*w
    zs[SWZ(p1)] = make_float2(Er - O1y, Ei + O1x);        // W[k]      = E + i*O1
    zs[SWZ(p2)] = make_float2(Er - O2y, O2x - Ei);        // W[4096-k] = conj(E) + i*O2
}

// ---------- conv: per (channel c, batch b); even/odd-packed real-conv via FFT-4096 ----------
// __launch_bounds__(256, 2): round-13's (256,4) made the compiler pick the 64-VGPR
// occupancy step and spill ~85MB/dispatch (WRITE 120MB vs 64). (NT,2)-style bounds gave
// this same dft16 butterfly 84-92 VGPR spill-free in round 7. 32KB LDS still allows
// 4 blocks/CU at <=128 VGPR.
template<int PACKED>
__global__ __launch_bounds__(256, 2) void conv_kernel(float* __restrict__ region,
                                                      const float* __restrict__ xg,
                                                      float* __restrict__ outg,
                                                      const float2* __restrict__ wt,
                                                      const float4* __restrict__ tsPall) {
    __shared__ float2 zs[4096];
    int wg  = blockIdx.x;
    int c   = (wg & 7) * 128 + ((wg >> 3) & 127);   // XCD swizzle: 128 contiguous c per XCD
    int b   = wg >> 10;
    int t   = threadIdx.x;

    float* slab = PACKED ? (region + ((size_t)c * BATCH + b) * NSEQ) : nullptr;

    // ---- fwd stage1 (H=256) fused with load: z[n] = x[2n] + i*x[2n+1], zero-padded
    {
        float2 v[16];
        #pragma unroll
        for (int q = 0; q < 8; ++q) {
            int n = t + 256*q;
            if (PACKED) v[q] = *(const float2*)(slab + 2*n);
            else {
                const float* xb = xg + (size_t)b * NSEQ * D + c;
                v[q] = make_float2(xb[(size_t)(2*n) * D], xb[(size_t)(2*n+1) * D]);
            }
        }
        #pragma unroll
        for (int q = 8; q < 16; ++q) v[q] = make_float2(0.f, 0.f);
        dft16<false>(v);
        twiddle_fwd(v, wt, 2*t);
        #pragma unroll
        for (int r = 0; r < 16; ++r) zs[SWZ(t + 256*r)] = v[r];
    }
    __syncthreads();
    pass16q<16, true,  false>(zs, wt, t); __syncthreads();
    pass16q<1,  false, false>(zs, wt, t); __syncthreads();

    // ---- untangle * T * repack (T slot-ordered coalesced; pairs race-free)
    const float4* tsP = tsPall + (size_t)c * 2049;
    #pragma unroll
    for (int it = 0; it < 8; ++it) {
        int k = ((t & 7) << 8) | ((t >> 3) << 3) | it;
        conv_pair(zs, wt, tsP[it * 256 + t], k);
    }
    if (t == 0) conv_pair(zs, wt, tsP[2048], 2048);
    __syncthreads();

    pass16q<1,  false, true>(zs, wt, t); __syncthreads();
    pass16q<16, true,  true>(zs, wt, t); __syncthreads();

    // ---- inv stage (H=256) fused with store: w[n] = y[2n] + i*y[2n+1]; keep n < 2048 only
    {
        float2 v[16];
        #pragma unroll
        for (int q = 0; q < 16; ++q) v[q] = zs[SWZ(t + 256*q)];
        twiddle_inv(v, wt, 2*t);
        dft16<true>(v);
        const float sc = 1.0f / 4096.0f;
        #pragma unroll
        for (int r = 0; r < 8; ++r) {
            int n = t + 256*r;
            float2 rv = make_float2(v[r].x * sc, v[r].y * sc);
            if (PACKED) *(float2*)(slab + 2*n) = rv;
            else {
                float* ob = outg + (size_t)b * NSEQ * D + c;
                ob[(size_t)(2*n) * D]   = rv.x;
                ob[(size_t)(2*n+1) * D] = rv.y;
            }
        }
    }
}

// ---------- pack: x(b,n,d) -> xQ[c][b][n] (deinterleaved channel-major) ----------
__global__ __launch_bounds__(256) void pack_xQ(const float* __restrict__ in,
                                               float* __restrict__ q) {
    __shared__ float tile[64][65];
    int tid = threadIdx.x;
    int n0 = blockIdx.x * 64, d0 = blockIdx.y * 64, b = blockIdx.z;
    const float* ib = in + (size_t)b * NSEQ * D;
    #pragma unroll
    for (int it = 0; it < 16; ++it) {
        int n_l = it * 4 + (tid >> 6);
        int d_l = tid & 63;
        tile[n_l][d_l] = ib[(size_t)(n0 + n_l) * D + d0 + d_l];
    }
    __syncthreads();
    #pragma unroll
    for (int it = 0; it < 16; ++it) {
        int flat = it * 256 + tid;
        int c_l = flat >> 6;
        int n_l = flat & 63;
        q[((size_t)(d0 + c_l) * BATCH + b) * NSEQ + n0 + n_l] = tile[n_l][c_l];
    }
}

// ---------- unpack: oQ[c][b][n] -> out(b,n,d) ----------
__global__ __launch_bounds__(256) void unpack_Q(const float* __restrict__ q,
                                                float* __restrict__ outp) {
    __shared__ float tile[64][65];
    int tid = threadIdx.x;
    int n0 = blockIdx.x * 64, d0 = blockIdx.y * 64, b = blockIdx.z;
    #pragma unroll
    for (int it = 0; it < 16; ++it) {
        int flat = it * 256 + tid;
        int c_l = flat >> 6;
        int n_l = flat & 63;
        tile[c_l][n_l] = q[((size_t)(d0 + c_l) * BATCH + b) * NSEQ + n0 + n_l];
    }
    __syncthreads();
    float* ob = outp + (size_t)b * NSEQ * D;
    #pragma unroll
    for (int it = 0; it < 16; ++it) {
        int n_l = it * 4 + (tid >> 6);
        int d_l = tid & 63;
        ob[(size_t)(n0 + n_l) * D + d0 + d_l] = tile[d_l][n_l];
    }
}

extern "C" void kernel_launch(void* const* d_in, const int* in_sizes, int n_in,
                              void* d_out, int out_size, void* d_ws, size_t ws_size,
                              hipStream_t stream) {
    const float* x = (const float*)d_in[0];   // (4, 4096, 1024) f32
    const float* t = (const float*)d_in[1];   // (8192, 1024) f32
    float* outp = (float*)d_out;              // (4, 4096, 1024) f32

    char* ws = (char*)d_ws;
    float2* wtab  = (float2*)ws;                                    // 32 KB used, 64 KB reserved
    float4* tsPall = (float4*)(ws + 65536);                         // 1024*2049*16 = 33,570,816
    const size_t OFF_Q = 65536 + (size_t)1024 * 2049 * 16;
    float* region = (float*)(ws + OFF_Q);                           // xQ/oQ in-place: 64 MB
    const size_t need_full = OFF_Q + (size_t)1024 * BATCH * NSEQ * sizeof(float); // ~96.1 MB

    wtab_init<<<16, 256, 0, stream>>>(wtab);
    tspec_kernel<<<NDP, NT, 0, stream>>>(t, wtab, tsPall);

    if (ws_size >= need_full) {
        pack_xQ<<<dim3(64, 16, BATCH), 256, 0, stream>>>(x, region);
        conv_kernel<1><<<1024 * BATCH, 256, 0, stream>>>(region, nullptr, nullptr, wtab, tsPall);
        unpack_Q<<<dim3(64, 16, BATCH), 256, 0, stream>>>(region, outp);
    } else {
        conv_kernel<0><<<1024 * BATCH, 256, 0, stream>>>(nullptr, x, outp, wtab, tsPall);
    }
}